// Round 3
// baseline (630.176 us; speedup 1.0000x reference)
//
#include <hip/hip_runtime.h>
#include <cstdint>
#include <cstddef>

#define DEV static __device__ __forceinline__

typedef __attribute__((ext_vector_type(8))) short bf16x8;
typedef __attribute__((ext_vector_type(4))) float f32x4;

#define T_SEQ 4096
#define CDIM  768
#define NH    12
#define HD    64
#define NBH   24            // B * NH
#define M_ROWS 8192         // B * T

// ---- workspace layout (bytes) ----
#define OFF_XB   0ull
#define OFF_WAT  (OFF_XB  + (size_t)M_ROWS * CDIM * 2)       // xb: [8192][768] bf16
#define OFF_WPT  (OFF_WAT + (size_t)(3*CDIM) * CDIM * 2)     // WaT: [2304][768] bf16
#define OFF_Q    (OFF_WPT + (size_t)CDIM * CDIM * 2)         // WpT: [768][768] bf16
#define OFF_K    (OFF_Q   + (size_t)NBH * T_SEQ * HD * 2)    // Q: [24][4096][64] bf16
#define OFF_VT   (OFF_K   + (size_t)NBH * T_SEQ * HD * 2)    // K: [24][4096][64] bf16
#define OFF_O    (OFF_VT  + (size_t)NBH * HD * T_SEQ * 2)    // Vt: [24][64][4096] bf16
// O: [8192][768] bf16

DEV unsigned short f2bf(float f) {            // RTNE f32 -> bf16
  unsigned u = __builtin_bit_cast(unsigned, f);
  u += 0x7FFFu + ((u >> 16) & 1u);
  return (unsigned short)(u >> 16);
}

DEV void gld_lds16(const void* g, void* l) {  // async global->LDS, 16B/lane, dest = wave-uniform base + lane*16
  __builtin_amdgcn_global_load_lds(
      (const __attribute__((address_space(1))) void*)g,
      (__attribute__((address_space(3))) void*)l, 16, 0, 0);
}

// ---------------- kernel 1: cast x f32 -> bf16 ----------------
__global__ __launch_bounds__(256) void k_conv(const float* __restrict__ in,
                                              unsigned short* __restrict__ out) {
  int i = blockIdx.x * 256 + threadIdx.x;     // one 8-elem chunk per thread, grid covers exactly
  const float4* p = (const float4*)in;
  float4 a = p[i * 2], b = p[i * 2 + 1];
  uint4 o;
  o.x = (unsigned)f2bf(a.x) | ((unsigned)f2bf(a.y) << 16);
  o.y = (unsigned)f2bf(a.z) | ((unsigned)f2bf(a.w) << 16);
  o.z = (unsigned)f2bf(b.x) | ((unsigned)f2bf(b.y) << 16);
  o.w = (unsigned)f2bf(b.z) | ((unsigned)f2bf(b.w) << 16);
  ((uint4*)out)[i] = o;
}

// ---------------- kernel 2: transpose [R][C] f32 -> [C][R] bf16 ----------------
__global__ __launch_bounds__(256) void k_transpose(const float* __restrict__ in,
                                                   unsigned short* __restrict__ out,
                                                   int R, int C) {
  __shared__ float tile[64][65];
  int c0 = blockIdx.x * 64, r0 = blockIdx.y * 64;
  int tid = threadIdx.x;
  for (int i = tid; i < 4096; i += 256) {
    int r = i >> 6, c = i & 63;
    tile[r][c] = in[(size_t)(r0 + r) * C + c0 + c];
  }
  __syncthreads();
  for (int i = tid; i < 4096; i += 256) {
    int c = i >> 6, r = i & 63;
    out[(size_t)(c0 + c) * R + r0 + r] = f2bf(tile[r][c]);
  }
}

// ---------------- kernel 3: QKV GEMM  [8192][768] @ [768][2304] (+bias) ----------------
// A = xb [M][768] bf16, Bt = WaT [2304][768] bf16 (row n = W_attn column n)
// 128x128 tile, BK=64, 4 waves (2x2), st_16x32 XOR swizzle in LDS.
__global__ __launch_bounds__(256) void k_qkv(const unsigned short* __restrict__ A,
                                             const unsigned short* __restrict__ Bt,
                                             const float* __restrict__ bias,
                                             unsigned short* __restrict__ Qo,
                                             unsigned short* __restrict__ Ko,
                                             unsigned short* __restrict__ Vt) {
  __shared__ short As[128 * 64];
  __shared__ short Bs[128 * 64];
  const int tid = threadIdx.x;
  const int wave = tid >> 6, lane = tid & 63;
  const int wr = wave >> 1, wc = wave & 1;
  const int m0 = blockIdx.y * 128, n0 = blockIdx.x * 128;

  f32x4 acc[4][4] = {};

#pragma unroll 1
  for (int k0 = 0; k0 < 768; k0 += 64) {
#pragma unroll
    for (int it = 0; it < 4; ++it) {
      int chunk = wave * 4 + it;
      int slot = chunk * 64 + lane;
      int row = slot >> 3, j = slot & 7;
      int kcol = k0 + ((j ^ (row & 7)) << 3);   // pre-swizzled global source (m173)
      gld_lds16(A  + (size_t)(m0 + row) * 768 + kcol, &As[chunk * 512]);
      gld_lds16(Bt + (size_t)(n0 + row) * 768 + kcol, &Bs[chunk * 512]);
    }
    __syncthreads();
#pragma unroll
    for (int kk = 0; kk < 2; ++kk) {
      bf16x8 af[4], bfr[4];
      int cbl = kk * 4 + (lane >> 4);
#pragma unroll
      for (int mi = 0; mi < 4; ++mi) {
        int row = wr * 64 + mi * 16 + (lane & 15);
        af[mi] = *(const bf16x8*)&As[(row * 8 + (cbl ^ (row & 7))) * 8];
      }
#pragma unroll
      for (int ni = 0; ni < 4; ++ni) {
        int row = wc * 64 + ni * 16 + (lane & 15);
        bfr[ni] = *(const bf16x8*)&Bs[(row * 8 + (cbl ^ (row & 7))) * 8];
      }
#pragma unroll
      for (int mi = 0; mi < 4; ++mi)
#pragma unroll
        for (int ni = 0; ni < 4; ++ni)
          acc[mi][ni] = __builtin_amdgcn_mfma_f32_16x16x32_bf16(af[mi], bfr[ni], acc[mi][ni], 0, 0, 0);
    }
    __syncthreads();
  }

  // epilogue: scatter to Q [bh][t][d], K [bh][t][d], Vt [bh][d][t]  (bf16)
  const int which = n0 / 768;   // whole 128-col tile lies in one of q/k/v (768 % 128 == 0)
#pragma unroll
  for (int ni = 0; ni < 4; ++ni) {
    int col = n0 + wc * 64 + ni * 16 + (lane & 15);
    int nr = col - which * 768;
    int h = nr >> 6, d = nr & 63;
    float bi = bias[col];
#pragma unroll
    for (int mi = 0; mi < 4; ++mi) {
      int mt = m0 + wr * 64 + mi * 16 + ((lane >> 4) << 2);
      int b = mt >> 12, t = mt & 4095;
      size_t bh = (size_t)(b * NH + h);
#pragma unroll
      for (int r = 0; r < 4; ++r) {
        unsigned short us = f2bf(acc[mi][ni][r] + bi);
        if (which == 0)
          Qo[bh * (T_SEQ * HD) + (size_t)(t + r) * HD + d] = us;
        else if (which == 1)
          Ko[bh * (T_SEQ * HD) + (size_t)(t + r) * HD + d] = us;
        else
          Vt[bh * (T_SEQ * HD) + (size_t)d * T_SEQ + (t + r)] = us;
      }
    }
  }
}

// ---------------- kernel 4: flash attention ----------------
// grid (32 qtiles, 24 bh). 4 waves x 32 q-rows. KV tile = 64 keys.
__global__ __launch_bounds__(256) void k_attn(const unsigned short* __restrict__ Q,
                                              const unsigned short* __restrict__ K,
                                              const unsigned short* __restrict__ Vt,
                                              unsigned short* __restrict__ O) {
  __shared__ short Ks[64 * 64];
  __shared__ short Vs[64 * 64];     // holds Vt tile: [d][k] (swizzled)
  __shared__ short Ps[4][32 * 64];  // per-wave P tile (swizzled)
  const int tid = threadIdx.x, wave = tid >> 6, lane = tid & 63;
  const int qt = blockIdx.x, bh = blockIdx.y;
  const int b = bh / NH, h = bh % NH;
  const size_t base = (size_t)bh * T_SEQ * HD;
  const int q0 = qt * 128 + wave * 32;
  const float SC = 0.18033688011112042f;  // 1/sqrt(64) * log2(e)

  // Q fragments in registers (A-operand layout: row = lane%16, k = 8*(lane/16)+j)
  bf16x8 aq[2][2];
#pragma unroll
  for (int mi = 0; mi < 2; ++mi)
#pragma unroll
    for (int kk = 0; kk < 2; ++kk)
      aq[mi][kk] = *(const bf16x8*)&Q[base + (size_t)(q0 + mi * 16 + (lane & 15)) * HD +
                                      kk * 32 + ((lane >> 4) << 3)];

  f32x4 oacc[2][4] = {};
  float mrow[2][4], lrow[2][4];
#pragma unroll
  for (int mi = 0; mi < 2; ++mi)
#pragma unroll
    for (int r = 0; r < 4; ++r) { mrow[mi][r] = -1e30f; lrow[mi][r] = 0.f; }

  short* Pw = &Ps[wave][0];

#pragma unroll 1
  for (int kt = 0; kt < 64; ++kt) {
    int k0 = kt * 64;
    // stage K tile [64 keys][64 d] and Vt tile [64 d][64 k], both XOR-swizzled
#pragma unroll
    for (int it = 0; it < 2; ++it) {
      int chunk = wave * 2 + it;
      int slot = chunk * 64 + lane;
      int row = slot >> 3, j = slot & 7;
      int coff = (j ^ (row & 7)) << 3;
      gld_lds16(K  + base + (size_t)(k0 + row) * HD + coff, &Ks[chunk * 512]);
      gld_lds16(Vt + base + (size_t)row * T_SEQ + k0 + coff, &Vs[chunk * 512]);
    }
    __syncthreads();

    // S = Q @ K^T
    f32x4 s[2][4] = {};
#pragma unroll
    for (int kk = 0; kk < 2; ++kk) {
      bf16x8 bk[4];
      int cbl = kk * 4 + (lane >> 4);
#pragma unroll
      for (int nb = 0; nb < 4; ++nb) {
        int row = nb * 16 + (lane & 15);
        bk[nb] = *(const bf16x8*)&Ks[(row * 8 + (cbl ^ (row & 7))) * 8];
      }
#pragma unroll
      for (int mi = 0; mi < 2; ++mi)
#pragma unroll
        for (int nb = 0; nb < 4; ++nb)
          s[mi][nb] = __builtin_amdgcn_mfma_f32_16x16x32_bf16(aq[mi][kk], bk[nb], s[mi][nb], 0, 0, 0);
    }

    // online softmax (log2 domain; D-layout: row q=(lane>>4)*4+r, col key=lane&15)
    float tmax[2][4];
#pragma unroll
    for (int mi = 0; mi < 2; ++mi)
#pragma unroll
      for (int r = 0; r < 4; ++r)
        tmax[mi][r] = fmaxf(fmaxf(s[mi][0][r], s[mi][1][r]), fmaxf(s[mi][2][r], s[mi][3][r]));
#pragma unroll
    for (int off = 1; off <= 8; off <<= 1)
#pragma unroll
      for (int mi = 0; mi < 2; ++mi)
#pragma unroll
        for (int r = 0; r < 4; ++r)
          tmax[mi][r] = fmaxf(tmax[mi][r], __shfl_xor(tmax[mi][r], off, 64));

    float al[2][4], rs[2][4];
    unsigned short pb[2][4][4];
#pragma unroll
    for (int mi = 0; mi < 2; ++mi)
#pragma unroll
      for (int r = 0; r < 4; ++r) {
        float mn = fmaxf(mrow[mi][r], tmax[mi][r]);
        al[mi][r] = exp2f((mrow[mi][r] - mn) * SC);
        mrow[mi][r] = mn;
        float rsum = 0.f;
#pragma unroll
        for (int nb = 0; nb < 4; ++nb) {
          float p = exp2f((s[mi][nb][r] - mn) * SC);
          pb[mi][nb][r] = f2bf(p);
          rsum += p;
        }
        rs[mi][r] = rsum;
      }
#pragma unroll
    for (int off = 1; off <= 8; off <<= 1)
#pragma unroll
      for (int mi = 0; mi < 2; ++mi)
#pragma unroll
        for (int r = 0; r < 4; ++r)
          rs[mi][r] += __shfl_xor(rs[mi][r], off, 64);
#pragma unroll
    for (int mi = 0; mi < 2; ++mi)
#pragma unroll
      for (int r = 0; r < 4; ++r)
        lrow[mi][r] = lrow[mi][r] * al[mi][r] + rs[mi][r];
#pragma unroll
    for (int mi = 0; mi < 2; ++mi)
#pragma unroll
      for (int nb = 0; nb < 4; ++nb)
#pragma unroll
        for (int r = 0; r < 4; ++r)
          oacc[mi][nb][r] *= al[mi][r];

    // write P (bf16) to per-wave LDS, swizzled
#pragma unroll
    for (int mi = 0; mi < 2; ++mi)
#pragma unroll
      for (int nb = 0; nb < 4; ++nb)
#pragma unroll
        for (int r = 0; r < 4; ++r) {
          int q = mi * 16 + ((lane >> 4) << 2) + r;
          int key = nb * 16 + (lane & 15);
          Pw[q * 64 + (((key >> 3) ^ (q & 7)) << 3) + (key & 7)] = (short)pb[mi][nb][r];
        }

    // O += P @ V   (B-operand from Vs: B[k][d] = Vt[d][k], k contiguous)
#pragma unroll
    for (int kk = 0; kk < 2; ++kk) {
      bf16x8 pa[2], bv[4];
      int cbl = kk * 4 + (lane >> 4);
#pragma unroll
      for (int mi = 0; mi < 2; ++mi) {
        int q = mi * 16 + (lane & 15);
        pa[mi] = *(const bf16x8*)&Pw[q * 64 + ((cbl ^ (q & 7)) << 3)];
      }
#pragma unroll
      for (int nb = 0; nb < 4; ++nb) {
        int dd = nb * 16 + (lane & 15);
        bv[nb] = *(const bf16x8*)&Vs[(dd * 8 + (cbl ^ (dd & 7))) * 8];
      }
#pragma unroll
      for (int mi = 0; mi < 2; ++mi)
#pragma unroll
        for (int nb = 0; nb < 4; ++nb)
          oacc[mi][nb] = __builtin_amdgcn_mfma_f32_16x16x32_bf16(pa[mi], bv[nb], oacc[mi][nb], 0, 0, 0);
    }
    __syncthreads();
  }

  // epilogue: O[b][t][h*64+d] bf16
  float inv[2][4];
#pragma unroll
  for (int mi = 0; mi < 2; ++mi)
#pragma unroll
    for (int r = 0; r < 4; ++r) inv[mi][r] = 1.0f / lrow[mi][r];
#pragma unroll
  for (int mi = 0; mi < 2; ++mi)
#pragma unroll
    for (int nb = 0; nb < 4; ++nb)
#pragma unroll
      for (int r = 0; r < 4; ++r) {
        int t = q0 + mi * 16 + ((lane >> 4) << 2) + r;
        int c = h * 64 + nb * 16 + (lane & 15);
        O[(size_t)(b * T_SEQ + t) * CDIM + c] = f2bf(oacc[mi][nb][r] * inv[mi][r]);
      }
}

// ---------------- kernel 5: proj GEMM  [8192][768] @ [768][768] + bias -> f32 ----------------
__global__ __launch_bounds__(256) void k_proj(const unsigned short* __restrict__ A,
                                              const unsigned short* __restrict__ Bt,
                                              const float* __restrict__ bias,
                                              float* __restrict__ out) {
  __shared__ short As[128 * 64];
  __shared__ short Bs[128 * 64];
  const int tid = threadIdx.x;
  const int wave = tid >> 6, lane = tid & 63;
  const int wr = wave >> 1, wc = wave & 1;
  const int m0 = blockIdx.y * 128, n0 = blockIdx.x * 128;

  f32x4 acc[4][4] = {};

#pragma unroll 1
  for (int k0 = 0; k0 < 768; k0 += 64) {
#pragma unroll
    for (int it = 0; it < 4; ++it) {
      int chunk = wave * 4 + it;
      int slot = chunk * 64 + lane;
      int row = slot >> 3, j = slot & 7;
      int kcol = k0 + ((j ^ (row & 7)) << 3);
      gld_lds16(A  + (size_t)(m0 + row) * 768 + kcol, &As[chunk * 512]);
      gld_lds16(Bt + (size_t)(n0 + row) * 768 + kcol, &Bs[chunk * 512]);
    }
    __syncthreads();
#pragma unroll
    for (int kk = 0; kk < 2; ++kk) {
      bf16x8 af[4], bfr[4];
      int cbl = kk * 4 + (lane >> 4);
#pragma unroll
      for (int mi = 0; mi < 4; ++mi) {
        int row = wr * 64 + mi * 16 + (lane & 15);
        af[mi] = *(const bf16x8*)&As[(row * 8 + (cbl ^ (row & 7))) * 8];
      }
#pragma unroll
      for (int ni = 0; ni < 4; ++ni) {
        int row = wc * 64 + ni * 16 + (lane & 15);
        bfr[ni] = *(const bf16x8*)&Bs[(row * 8 + (cbl ^ (row & 7))) * 8];
      }
#pragma unroll
      for (int mi = 0; mi < 4; ++mi)
#pragma unroll
        for (int ni = 0; ni < 4; ++ni)
          acc[mi][ni] = __builtin_amdgcn_mfma_f32_16x16x32_bf16(af[mi], bfr[ni], acc[mi][ni], 0, 0, 0);
    }
    __syncthreads();
  }

#pragma unroll
  for (int ni = 0; ni < 4; ++ni) {
    int col = n0 + wc * 64 + ni * 16 + (lane & 15);
    float bi = bias[col];
#pragma unroll
    for (int mi = 0; mi < 4; ++mi) {
      int mt = m0 + wr * 64 + mi * 16 + ((lane >> 4) << 2);
#pragma unroll
      for (int r = 0; r < 4; ++r)
        out[(size_t)(mt + r) * CDIM + col] = acc[mi][ni][r] + bi;
    }
  }
}

extern "C" void kernel_launch(void* const* d_in, const int* in_sizes, int n_in,
                              void* d_out, int out_size, void* d_ws, size_t ws_size,
                              hipStream_t stream) {
  const float* x  = (const float*)d_in[0];
  const float* Wa = (const float*)d_in[1];
  const float* ba = (const float*)d_in[2];
  const float* Wp = (const float*)d_in[3];
  const float* bp = (const float*)d_in[4];

  char* ws = (char*)d_ws;
  unsigned short* xb  = (unsigned short*)(ws + OFF_XB);
  unsigned short* WaT = (unsigned short*)(ws + OFF_WAT);
  unsigned short* WpT = (unsigned short*)(ws + OFF_WPT);
  unsigned short* Qb  = (unsigned short*)(ws + OFF_Q);
  unsigned short* Kb  = (unsigned short*)(ws + OFF_K);
  unsigned short* Vtb = (unsigned short*)(ws + OFF_VT);
  unsigned short* Ob  = (unsigned short*)(ws + OFF_O);

  k_conv<<<3072, 256, 0, stream>>>(x, xb);                                   // 8192*768/8/256
  k_transpose<<<dim3(36, 12), 256, 0, stream>>>(Wa, WaT, CDIM, 3 * CDIM);
  k_transpose<<<dim3(12, 12), 256, 0, stream>>>(Wp, WpT, CDIM, CDIM);
  k_qkv<<<dim3(18, 64), 256, 0, stream>>>(xb, WaT, ba, Qb, Kb, Vtb);
  k_attn<<<dim3(32, 24), 256, 0, stream>>>(Qb, Kb, Vtb, Ob);
  k_proj<<<dim3(6, 64), 256, 0, stream>>>(Ob, WpT, bp, (float*)d_out);
}

// Round 4
// 291.245 us; speedup vs baseline: 2.1637x; 2.1637x over previous
//
#include <hip/hip_runtime.h>
#include <cstdint>
#include <cstddef>

#define DEV static __device__ __forceinline__

typedef __attribute__((ext_vector_type(8))) short bf16x8;
typedef __attribute__((ext_vector_type(4))) float f32x4;
typedef __attribute__((ext_vector_type(16))) float f32x16;

#define T_SEQ 4096
#define CDIM  768
#define NH    12
#define HD    64
#define NBH   24            // B * NH
#define M_ROWS 8192         // B * T

// ---- workspace layout (bytes) ----
#define OFF_XB   0ull
#define OFF_WAT  (OFF_XB  + (size_t)M_ROWS * CDIM * 2)       // xb: [8192][768] bf16
#define OFF_WPT  (OFF_WAT + (size_t)(3*CDIM) * CDIM * 2)     // WaT: [2304][768] bf16
#define OFF_Q    (OFF_WPT + (size_t)CDIM * CDIM * 2)         // WpT: [768][768] bf16
#define OFF_K    (OFF_Q   + (size_t)NBH * T_SEQ * HD * 2)    // Q: [24][4096][64] bf16
#define OFF_VT   (OFF_K   + (size_t)NBH * T_SEQ * HD * 2)    // K: [24][4096][64] bf16
#define OFF_O    (OFF_VT  + (size_t)NBH * HD * T_SEQ * 2)    // Vt: [24][64][4096] bf16
// O: [8192][768] bf16

DEV unsigned short f2bf(float f) {            // RTNE f32 -> bf16
  unsigned u = __builtin_bit_cast(unsigned, f);
  u += 0x7FFFu + ((u >> 16) & 1u);
  return (unsigned short)(u >> 16);
}

DEV void gld_lds16(const void* g, void* l) {  // async global->LDS, 16B/lane, dest = wave-uniform base + lane*16
  __builtin_amdgcn_global_load_lds(
      (const __attribute__((address_space(1))) void*)g,
      (__attribute__((address_space(3))) void*)l, 16, 0, 0);
}

// ---------------- kernel 1: cast x f32 -> bf16 ----------------
__global__ __launch_bounds__(256) void k_conv(const float* __restrict__ in,
                                              unsigned short* __restrict__ out) {
  int i = blockIdx.x * 256 + threadIdx.x;
  const float4* p = (const float4*)in;
  float4 a = p[i * 2], b = p[i * 2 + 1];
  uint4 o;
  o.x = (unsigned)f2bf(a.x) | ((unsigned)f2bf(a.y) << 16);
  o.y = (unsigned)f2bf(a.z) | ((unsigned)f2bf(a.w) << 16);
  o.z = (unsigned)f2bf(b.x) | ((unsigned)f2bf(b.y) << 16);
  o.w = (unsigned)f2bf(b.z) | ((unsigned)f2bf(b.w) << 16);
  ((uint4*)out)[i] = o;
}

// ---------------- kernel 2: transpose [R][C] f32 -> [C][R] bf16 ----------------
__global__ __launch_bounds__(256) void k_transpose(const float* __restrict__ in,
                                                   unsigned short* __restrict__ out,
                                                   int R, int C) {
  __shared__ float tile[64][65];
  int c0 = blockIdx.x * 64, r0 = blockIdx.y * 64;
  int tid = threadIdx.x;
  for (int i = tid; i < 4096; i += 256) {
    int r = i >> 6, c = i & 63;
    tile[r][c] = in[(size_t)(r0 + r) * C + c0 + c];
  }
  __syncthreads();
  for (int i = tid; i < 4096; i += 256) {
    int c = i >> 6, r = i & 63;
    out[(size_t)(c0 + c) * R + r0 + r] = f2bf(tile[r][c]);
  }
}

// ---------------- kernel 3: QKV GEMM  [8192][768] @ [768][2304] (+bias) ----------------
__global__ __launch_bounds__(256) void k_qkv(const unsigned short* __restrict__ A,
                                             const unsigned short* __restrict__ Bt,
                                             const float* __restrict__ bias,
                                             unsigned short* __restrict__ Qo,
                                             unsigned short* __restrict__ Ko,
                                             unsigned short* __restrict__ Vt) {
  __shared__ short As[128 * 64];
  __shared__ short Bs[128 * 64];
  const int tid = threadIdx.x;
  const int wave = tid >> 6, lane = tid & 63;
  const int wr = wave >> 1, wc = wave & 1;
  const int m0 = blockIdx.y * 128, n0 = blockIdx.x * 128;

  f32x4 acc[4][4] = {};

#pragma unroll 1
  for (int k0 = 0; k0 < 768; k0 += 64) {
#pragma unroll
    for (int it = 0; it < 4; ++it) {
      int chunk = wave * 4 + it;
      int slot = chunk * 64 + lane;
      int row = slot >> 3, j = slot & 7;
      int kcol = k0 + ((j ^ (row & 7)) << 3);
      gld_lds16(A  + (size_t)(m0 + row) * 768 + kcol, &As[chunk * 512]);
      gld_lds16(Bt + (size_t)(n0 + row) * 768 + kcol, &Bs[chunk * 512]);
    }
    __syncthreads();
#pragma unroll
    for (int kk = 0; kk < 2; ++kk) {
      bf16x8 af[4], bfr[4];
      int cbl = kk * 4 + (lane >> 4);
#pragma unroll
      for (int mi = 0; mi < 4; ++mi) {
        int row = wr * 64 + mi * 16 + (lane & 15);
        af[mi] = *(const bf16x8*)&As[(row * 8 + (cbl ^ (row & 7))) * 8];
      }
#pragma unroll
      for (int ni = 0; ni < 4; ++ni) {
        int row = wc * 64 + ni * 16 + (lane & 15);
        bfr[ni] = *(const bf16x8*)&Bs[(row * 8 + (cbl ^ (row & 7))) * 8];
      }
#pragma unroll
      for (int mi = 0; mi < 4; ++mi)
#pragma unroll
        for (int ni = 0; ni < 4; ++ni)
          acc[mi][ni] = __builtin_amdgcn_mfma_f32_16x16x32_bf16(af[mi], bfr[ni], acc[mi][ni], 0, 0, 0);
    }
    __syncthreads();
  }

  const int which = n0 / 768;
#pragma unroll
  for (int ni = 0; ni < 4; ++ni) {
    int col = n0 + wc * 64 + ni * 16 + (lane & 15);
    int nr = col - which * 768;
    int h = nr >> 6, d = nr & 63;
    float bi = bias[col];
#pragma unroll
    for (int mi = 0; mi < 4; ++mi) {
      int mt = m0 + wr * 64 + mi * 16 + ((lane >> 4) << 2);
      int b = mt >> 12, t = mt & 4095;
      size_t bh = (size_t)(b * NH + h);
#pragma unroll
      for (int r = 0; r < 4; ++r) {
        unsigned short us = f2bf(acc[mi][ni][r] + bi);
        if (which == 0)
          Qo[bh * (T_SEQ * HD) + (size_t)(t + r) * HD + d] = us;
        else if (which == 1)
          Ko[bh * (T_SEQ * HD) + (size_t)(t + r) * HD + d] = us;
        else
          Vt[bh * (T_SEQ * HD) + (size_t)d * T_SEQ + (t + r)] = us;
      }
    }
  }
}

// ---------------- kernel 4: flash attention (swapped-QK^T, 32x32 MFMA, in-reg softmax) ----------------
// grid (32 qtiles, 24 bh). 4 waves x 32 q-rows. KV tile = 64 keys, double-buffered.
__global__ __launch_bounds__(256, 3) void k_attn(const unsigned short* __restrict__ Q,
                                                 const unsigned short* __restrict__ K,
                                                 const unsigned short* __restrict__ Vt,
                                                 unsigned short* __restrict__ O) {
  __shared__ short lds[2][2][64 * 64];   // [buf][K|Vt][64 rows x 64 cols], XOR-swizzled
  const int tid = threadIdx.x, wave = tid >> 6, lane = tid & 63;
  const int hi = lane >> 5, l31 = lane & 31;
  const int qt = blockIdx.x, bh = blockIdx.y;
  const int b = bh / NH, h = bh % NH;
  const size_t base = (size_t)bh * T_SEQ * HD;
  const int q0 = qt * 128 + wave * 32;
  const float SC = 0.18033688011112042f;   // log2(e)/sqrt(64)
  const float THR = 44.3614f;              // 8 / SC (defer-max threshold, raw score units)

  // Q fragments (B-operand): col=q=l31, k(d) = 16t + 8*hi + j
  bf16x8 aq[4];
#pragma unroll
  for (int t = 0; t < 4; ++t)
    aq[t] = *(const bf16x8*)&Q[base + (size_t)(q0 + l31) * HD + t * 16 + hi * 8];

  f32x16 oacc0 = {}, oacc1 = {};
  float m = -1e30f, l = 0.f;

  auto STAGE = [&](int bufi, int k0) {
#pragma unroll
    for (int it = 0; it < 2; ++it) {
      int chunk = wave * 2 + it;
      int slot = chunk * 64 + lane;
      int row = slot >> 3, j = slot & 7;
      int ce = ((j ^ (row & 7)) << 3);     // pre-swizzled source column (elements)
      gld_lds16(K  + base + (size_t)(k0 + row) * HD + ce, &lds[bufi][0][chunk * 512]);
      gld_lds16(Vt + base + (size_t)row * T_SEQ + k0 + ce, &lds[bufi][1][chunk * 512]);
    }
  };

  STAGE(0, 0);
  __syncthreads();

  int buf = 0;
#pragma unroll 1
  for (int kt = 0; kt < 64; ++kt) {
    if (kt < 63) STAGE(buf ^ 1, (kt + 1) * 64);
    const short* Kb = lds[buf][0];
    const short* Vb = lds[buf][1];
#pragma unroll
    for (int kb = 0; kb < 2; ++kb) {
      // S^T = K_tile @ Q^T : s[key][q], col=q=l31, key=(r&3)+8*(r>>2)+4*hi (+32*kb)
      f32x16 s = {};
      {
        int row = kb * 32 + l31;
        int rsw = row & 7;
        const short* Kr = &Kb[row * 64];
#pragma unroll
        for (int t = 0; t < 4; ++t) {
          bf16x8 kf = *(const bf16x8*)&Kr[8 * (((t << 1) | hi) ^ rsw)];
          s = __builtin_amdgcn_mfma_f32_32x32x16_bf16(kf, aq[t], s, 0, 0, 0);
        }
      }
      // --- online softmax, fully in-register ---
      float tm = s[0];
#pragma unroll
      for (int r = 1; r < 16; ++r) tm = fmaxf(tm, s[r]);
      tm = fmaxf(tm, __shfl_xor(tm, 32, 64));
      if (!__all(tm <= m + THR)) {          // rare rescale path (T13 defer-max)
        float mn = fmaxf(m, tm);
        float al = exp2f((m - mn) * SC);
        l *= al;
#pragma unroll
        for (int r = 0; r < 16; ++r) {
          float alt = __shfl(al, ((r & 3) + 8 * (r >> 2)) + 4 * hi, 64);
          oacc0[r] *= alt;
          oacc1[r] *= alt;
        }
        m = mn;
      }
      float c = -m * SC;
#pragma unroll
      for (int r = 0; r < 16; ++r) s[r] = exp2f(s[r] * SC + c);   // P values (<= 2^8)
      float rs = 0.f;
#pragma unroll
      for (int r = 0; r < 16; ++r) rs += s[r];
      rs += __shfl_xor(rs, 32, 64);
      l += rs;
      // pack P -> bf16 A-fragments in NATURAL register order (no cross-lane moves);
      // V B-fragments below use the SAME key permutation sigma(j)=(j&3)+8*(j>>2)+4*hi.
      unsigned w[8];
#pragma unroll
      for (int i = 0; i < 8; ++i) {
        unsigned wi;
        asm("v_cvt_pk_bf16_f32 %0, %1, %2" : "=v"(wi) : "v"(s[2 * i]), "v"(s[2 * i + 1]));
        w[i] = wi;
      }
      union { unsigned u[4]; bf16x8 v; } pf0, pf1;
      pf0.u[0] = w[0]; pf0.u[1] = w[1]; pf0.u[2] = w[2]; pf0.u[3] = w[3];
      pf1.u[0] = w[4]; pf1.u[1] = w[5]; pf1.u[2] = w[6]; pf1.u[3] = w[7];
      // O += P @ V ; B-frag element j = Vt[d][32kb+16ks+sigma(j)] -> two ds_read_b64 per frag
#pragma unroll
      for (int db = 0; db < 2; ++db) {
        int vrow = db * 32 + l31;
        int vsw = (vrow & 7) << 4;
        const char* Vr = (const char*)&Vb[vrow * 64];
#pragma unroll
        for (int ks = 0; ks < 2; ++ks) {
          int b16 = kb * 64 + ks * 32;     // byte base of k-slice within row
          union { unsigned long long q[2]; bf16x8 v; } vf;
          vf.q[0] = *(const unsigned long long*)(Vr + (((b16 +  0) ^ vsw) + 8 * hi));
          vf.q[1] = *(const unsigned long long*)(Vr + (((b16 + 16) ^ vsw) + 8 * hi));
          if (db == 0)
            oacc0 = __builtin_amdgcn_mfma_f32_32x32x16_bf16(ks ? pf1.v : pf0.v, vf.v, oacc0, 0, 0, 0);
          else
            oacc1 = __builtin_amdgcn_mfma_f32_32x32x16_bf16(ks ? pf1.v : pf0.v, vf.v, oacc1, 0, 0, 0);
        }
      }
    }
    __syncthreads();
    buf ^= 1;
  }

  // epilogue: O[b][t][h*64+d], d = db*32 + l31, t rows via D-layout
#pragma unroll
  for (int r = 0; r < 16; ++r) {
    float lt = __shfl(l, ((r & 3) + 8 * (r >> 2)) + 4 * hi, 64);
    float inv = 1.0f / lt;
    int t = q0 + ((r & 3) + 8 * (r >> 2)) + 4 * hi;
    size_t rowb = (size_t)(b * T_SEQ + t) * CDIM + h * 64;
    O[rowb + l31]      = f2bf(oacc0[r] * inv);
    O[rowb + 32 + l31] = f2bf(oacc1[r] * inv);
  }
}

// ---------------- kernel 5: proj GEMM  [8192][768] @ [768][768] + bias -> f32 ----------------
__global__ __launch_bounds__(256) void k_proj(const unsigned short* __restrict__ A,
                                              const unsigned short* __restrict__ Bt,
                                              const float* __restrict__ bias,
                                              float* __restrict__ out) {
  __shared__ short As[128 * 64];
  __shared__ short Bs[128 * 64];
  const int tid = threadIdx.x;
  const int wave = tid >> 6, lane = tid & 63;
  const int wr = wave >> 1, wc = wave & 1;
  const int m0 = blockIdx.y * 128, n0 = blockIdx.x * 128;

  f32x4 acc[4][4] = {};

#pragma unroll 1
  for (int k0 = 0; k0 < 768; k0 += 64) {
#pragma unroll
    for (int it = 0; it < 4; ++it) {
      int chunk = wave * 4 + it;
      int slot = chunk * 64 + lane;
      int row = slot >> 3, j = slot & 7;
      int kcol = k0 + ((j ^ (row & 7)) << 3);
      gld_lds16(A  + (size_t)(m0 + row) * 768 + kcol, &As[chunk * 512]);
      gld_lds16(Bt + (size_t)(n0 + row) * 768 + kcol, &Bs[chunk * 512]);
    }
    __syncthreads();
#pragma unroll
    for (int kk = 0; kk < 2; ++kk) {
      bf16x8 af[4], bfr[4];
      int cbl = kk * 4 + (lane >> 4);
#pragma unroll
      for (int mi = 0; mi < 4; ++mi) {
        int row = wr * 64 + mi * 16 + (lane & 15);
        af[mi] = *(const bf16x8*)&As[(row * 8 + (cbl ^ (row & 7))) * 8];
      }
#pragma unroll
      for (int ni = 0; ni < 4; ++ni) {
        int row = wc * 64 + ni * 16 + (lane & 15);
        bfr[ni] = *(const bf16x8*)&Bs[(row * 8 + (cbl ^ (row & 7))) * 8];
      }
#pragma unroll
      for (int mi = 0; mi < 4; ++mi)
#pragma unroll
        for (int ni = 0; ni < 4; ++ni)
          acc[mi][ni] = __builtin_amdgcn_mfma_f32_16x16x32_bf16(af[mi], bfr[ni], acc[mi][ni], 0, 0, 0);
    }
    __syncthreads();
  }

#pragma unroll
  for (int ni = 0; ni < 4; ++ni) {
    int col = n0 + wc * 64 + ni * 16 + (lane & 15);
    float bi = bias[col];
#pragma unroll
    for (int mi = 0; mi < 4; ++mi) {
      int mt = m0 + wr * 64 + mi * 16 + ((lane >> 4) << 2);
#pragma unroll
      for (int r = 0; r < 4; ++r)
        out[(size_t)(mt + r) * CDIM + col] = acc[mi][ni][r] + bi;
    }
  }
}

extern "C" void kernel_launch(void* const* d_in, const int* in_sizes, int n_in,
                              void* d_out, int out_size, void* d_ws, size_t ws_size,
                              hipStream_t stream) {
  const float* x  = (const float*)d_in[0];
  const float* Wa = (const float*)d_in[1];
  const float* ba = (const float*)d_in[2];
  const float* Wp = (const float*)d_in[3];
  const float* bp = (const float*)d_in[4];

  char* ws = (char*)d_ws;
  unsigned short* xb  = (unsigned short*)(ws + OFF_XB);
  unsigned short* WaT = (unsigned short*)(ws + OFF_WAT);
  unsigned short* WpT = (unsigned short*)(ws + OFF_WPT);
  unsigned short* Qb  = (unsigned short*)(ws + OFF_Q);
  unsigned short* Kb  = (unsigned short*)(ws + OFF_K);
  unsigned short* Vtb = (unsigned short*)(ws + OFF_VT);
  unsigned short* Ob  = (unsigned short*)(ws + OFF_O);

  k_conv<<<3072, 256, 0, stream>>>(x, xb);
  k_transpose<<<dim3(36, 12), 256, 0, stream>>>(Wa, WaT, CDIM, 3 * CDIM);
  k_transpose<<<dim3(12, 12), 256, 0, stream>>>(Wp, WpT, CDIM, CDIM);
  k_qkv<<<dim3(18, 64), 256, 0, stream>>>(xb, WaT, ba, Qb, Kb, Vtb);
  k_attn<<<dim3(32, 24), 256, 0, stream>>>(Qb, Kb, Vtb, Ob);
  k_proj<<<dim3(6, 64), 256, 0, stream>>>(Ob, WpT, bp, (float*)d_out);
}